// Round 7
// baseline (1645.887 us; speedup 1.0000x reference)
//
#include <hip/hip_runtime.h>
#include <math.h>

#define BN 8
#define HW 4096
#define NH 128
#define SNC 35
#define SD 512

typedef __attribute__((ext_vector_type(8))) short short8v;
typedef __attribute__((ext_vector_type(4))) short short4v;
typedef __attribute__((ext_vector_type(4))) float float4v;
typedef __attribute__((ext_vector_type(16))) float float16v;
typedef __attribute__((ext_vector_type(4))) unsigned int uint4v;

__device__ __forceinline__ short f2bf(float f) {
  unsigned u = __float_as_uint(f);
  unsigned r = (u + 0x7fffu + ((u >> 16) & 1u)) >> 16;
  return (short)r;
}
__device__ __forceinline__ float bf2f(short h) {
  return __uint_as_float(((unsigned)(unsigned short)h) << 16);
}

// ---------------- per-(b,c) instance-norm stats ----------------
__global__ __launch_bounds__(256) void stats_kernel(const float* __restrict__ x,
                                                    float* __restrict__ mu,
                                                    float* __restrict__ rstd) {
  int row = blockIdx.x;
  const float* p = x + (size_t)row * HW;
  float s = 0.f, s2 = 0.f;
  for (int i = threadIdx.x; i < HW; i += 256) {
    float v = p[i];
    s += v; s2 += v * v;
  }
  #pragma unroll
  for (int off = 32; off > 0; off >>= 1) {
    s  += __shfl_down(s, off);
    s2 += __shfl_down(s2, off);
  }
  __shared__ float as[4], as2[4];
  int wid = threadIdx.x >> 6;
  if ((threadIdx.x & 63) == 0) { as[wid] = s; as2[wid] = s2; }
  __syncthreads();
  if (threadIdx.x == 0) {
    float t  = as[0] + as[1] + as[2] + as[3];
    float t2 = as2[0] + as2[1] + as2[2] + as2[3];
    float m = t * (1.f / HW);
    float var = t2 * (1.f / HW) - m * m;
    mu[row] = m;
    rstd[row] = rsqrtf(var + 1e-5f);
  }
}

// ---------------- style modulation s[b,i] ----------------
__global__ __launch_bounds__(256) void modscale_kernel(const float* __restrict__ style,
                                                       const float* __restrict__ mw,
                                                       const float* __restrict__ mb,
                                                       float* __restrict__ s_out, int I) {
  int idx = blockIdx.x * 256 + threadIdx.x;
  if (idx >= BN * I) return;
  int b = idx / I, i = idx - b * I;
  const float* st = style + (size_t)b * SD;
  const float* w  = mw + (size_t)i * SD;
  float acc = 0.f;
  for (int d = 0; d < SD; ++d) acc += st[d] * w[d];
  s_out[idx] = acc * 0.044194173824159216f + mb[i];
}

// ---------------- sum of w^2 over taps ----------------
__global__ __launch_bounds__(256) void wsq_kernel(const float* __restrict__ w,
                                                  float* __restrict__ wsq, int n, int KK) {
  int idx = blockIdx.x * 256 + threadIdx.x;
  if (idx >= n) return;
  const float* p = w + (size_t)idx * KK;
  float a = 0.f;
  for (int t = 0; t < KK; ++t) a += p[t] * p[t];
  wsq[idx] = a;
}

// ---------------- dscale[b,o] = demod * conv_scale ----------------
__global__ __launch_bounds__(256) void demod_kernel(const float* __restrict__ wsq,
                                                    const float* __restrict__ s,
                                                    float* __restrict__ dscale,
                                                    int I, float cs) {
  int idx = blockIdx.x * 256 + threadIdx.x;
  if (idx >= BN * 256) return;
  int b = idx >> 8, o = idx & 255;
  const float* wr = wsq + (size_t)o * I;
  const float* sr = s + (size_t)b * I;
  float a = 0.f;
  for (int i = 0; i < I; ++i) { float sv = sr[i]; a += wr[i] * sv * sv; }
  float demod = rsqrtf(cs * cs * a + 1e-8f);
  dscale[idx] = demod * cs;
}

// ---------------- weight pack for 32x32x16 frags: hi/lo bf16 ----------------
// packed[((tap*OCT32 + ocT)*IK + ik)*64 + lane][8]
//   po = ocT*32 + (lane&31), ic = ik*16 + (lane>>5)*8 + j
// interleave8: po -> is_beta=(po>>3)&1, channel c=(po>>4)*8 + (po&7)
__global__ __launch_bounds__(256) void pack_w32_kernel(const float* __restrict__ wg,
                                                       const float* __restrict__ wb,
                                                       short* __restrict__ ph,
                                                       short* __restrict__ pl,
                                                       int OCtot, int IC, int KK,
                                                       int interleave8) {
  int tid = blockIdx.x * 256 + threadIdx.x;
  int IK = IC / 16, OCT32 = OCtot / 32;
  int total = KK * OCT32 * IK * 64;
  if (tid >= total) return;
  int lane = tid & 63;
  int r = tid >> 6;
  int ik = r % IK; r /= IK;
  int ocT = r % OCT32; int tap = r / OCT32;
  int po = ocT * 32 + (lane & 31);
  int ic0 = ik * 16 + (lane >> 5) * 8;
  const float* srcw;
  int oc;
  if (interleave8) { oc = ((po >> 4) << 3) + (po & 7); srcw = ((po >> 3) & 1) ? wb : wg; }
  else { oc = po; srcw = wg; }
  short8v hv, lv;
  #pragma unroll
  for (int j = 0; j < 8; ++j) {
    float v = srcw[((size_t)oc * IC + ic0 + j) * KK + tap];
    short h = f2bf(v);
    hv[j] = h;
    lv[j] = f2bf(v - bf2f(h));
  }
  size_t o = (size_t)tid * 8;
  *(short8v*)(ph + o) = hv;
  *(short8v*)(pl + o) = lv;
}

// ---------------- all 3 seg convs (35->3x128) 3x3 + bias + relu, pixel-major hi/lo [B][HW][384] ----------------
__global__ __launch_bounds__(256) void seg_conv_all_kernel(
    const float* __restrict__ seg,
    const float* __restrict__ sw0, const float* __restrict__ sb0,
    const float* __restrict__ sw1, const float* __restrict__ sb1,
    const float* __restrict__ sw2, const float* __restrict__ sb2,
    short* __restrict__ actv_hi, short* __restrict__ actv_lo) {
  const int b = blockIdx.x;
  const int ty0 = (blockIdx.y >> 1) * 32, tx0 = (blockIdx.y & 1) * 32;
  const int s = blockIdx.z >> 3;
  const int oc0 = (blockIdx.z & 7) * 16;
  const float* sw = (s == 0) ? sw0 : ((s == 1) ? sw1 : sw2);
  const float* sb = (s == 0) ? sb0 : ((s == 1) ? sb1 : sb2);
  const int t = threadIdx.x;
  const int c = t & 31;
  const int r0 = (t >> 5) * 4;
  __shared__ float lds_in[12 * 34 * 34];
  __shared__ float lds_w[12 * 9 * 16];
  float acc[4][16];
  #pragma unroll
  for (int q = 0; q < 4; ++q)
    #pragma unroll
    for (int o = 0; o < 16; ++o) acc[q][o] = 0.f;

  for (int ic0 = 0; ic0 < SNC; ic0 += 12) {
    int icc = (SNC - ic0 < 12) ? (SNC - ic0) : 12;
    __syncthreads();
    for (int idx = t; idx < icc * 34 * 34; idx += 256) {
      int ic = idx / (34 * 34);
      int rem = idx - ic * (34 * 34);
      int y = rem / 34, xx = rem - y * 34;
      int gy = ty0 + y - 1, gx = tx0 + xx - 1;
      float v = 0.f;
      if (gy >= 0 && gy < 64 && gx >= 0 && gx < 64)
        v = seg[(((size_t)b * SNC + ic0 + ic) * 64 + gy) * 64 + gx];
      lds_in[idx] = v;
    }
    for (int idx = t; idx < icc * 9 * 16; idx += 256) {
      int oc = idx & 15;
      int rest = idx >> 4;
      int ic = rest / 9, tau = rest - ic * 9;
      lds_w[idx] = sw[((size_t)(oc0 + oc) * SNC + ic0 + ic) * 9 + tau];
    }
    __syncthreads();
    for (int ic = 0; ic < icc; ++ic) {
      #pragma unroll
      for (int kh = 0; kh < 3; ++kh) {
        int base = (ic * 34 + r0 + kh) * 34 + c;
        #pragma unroll
        for (int kw = 0; kw < 3; ++kw) {
          float a0 = lds_in[base + kw];
          float a1 = lds_in[base + kw + 34];
          float a2 = lds_in[base + kw + 68];
          float a3 = lds_in[base + kw + 102];
          const float* wp = &lds_w[(ic * 9 + kh * 3 + kw) * 16];
          float wv[16];
          *(float4*)&wv[0]  = *(const float4*)&wp[0];
          *(float4*)&wv[4]  = *(const float4*)&wp[4];
          *(float4*)&wv[8]  = *(const float4*)&wp[8];
          *(float4*)&wv[12] = *(const float4*)&wp[12];
          #pragma unroll
          for (int o = 0; o < 16; ++o) {
            acc[0][o] += a0 * wv[o];
            acc[1][o] += a1 * wv[o];
            acc[2][o] += a2 * wv[o];
            acc[3][o] += a3 * wv[o];
          }
        }
      }
    }
  }
  float bias[16];
  #pragma unroll
  for (int o = 0; o < 16; ++o) bias[o] = sb[oc0 + o];
  #pragma unroll
  for (int q = 0; q < 4; ++q) {
    int px = (ty0 + r0 + q) * 64 + tx0 + c;
    short8v h0, h1, l0, l1;
    #pragma unroll
    for (int o = 0; o < 8; ++o) {
      float v = fmaxf(acc[q][o] + bias[o], 0.f);
      short h = f2bf(v); h0[o] = h; l0[o] = f2bf(v - bf2f(h));
      float v2 = fmaxf(acc[q][o + 8] + bias[o + 8], 0.f);
      short h2 = f2bf(v2); h1[o] = h2; l1[o] = f2bf(v2 - bf2f(h2));
    }
    size_t o0 = ((size_t)b * HW + px) * 384 + s * 128 + oc0;
    *(short8v*)(actv_hi + o0) = h0;
    *(short8v*)(actv_hi + o0 + 8) = h1;
    *(short8v*)(actv_lo + o0) = l0;
    *(short8v*)(actv_lo + o0 + 8) = l1;
  }
}

// ---------------- 32x32x16 MFMA split-precision implicit-GEMM conv ----------------
// Block: 128 oc x 128 px (2 rows x 64 cols), 4 waves = 2 ocg x 2 colg.
// A-fragment SW pipeline: double-buffered regs, cluster c+1's 12 loads issued
// during cluster c's 36 MFMAs (cross-icC prefetch too). Staging (T14): loads for
// icC+1 issued inside cluster 0 (after c=1's A-loads in the vmcnt FIFO, so they
// never block an A-wait); regs->LDS written between barriers at top of icC+1.
template<int IC, int ICSTRIDE, int K3, int GBMODE, int LRELU, int ACCUM>
__global__ __launch_bounds__(256) void conv32_kernel(
    const short* __restrict__ in_hi, const short* __restrict__ in_lo,
    const short* __restrict__ wp_hi, const short* __restrict__ wp_lo,
    const float* __restrict__ dscale,
    const float* __restrict__ src, const float* __restrict__ mu,
    const float* __restrict__ rstd, const float* __restrict__ gbias,
    const float* __restrict__ bbias, const float* __restrict__ sscale,
    float* __restrict__ outF, short* __restrict__ out_hi,
    short* __restrict__ out_lo, int OCT32, int C, int icbase) {
  const int b = blockIdx.x;
  const int r0 = blockIdx.y * 2;
  const int z = blockIdx.z;
  const int t = threadIdx.x;
  const int ocg = (t >> 6) & 1;
  const int colg = t >> 7;
  const int lane = t & 63;
  const int l31 = lane & 31, hl = lane >> 5;
  const int ICC = IC / 32;
  const int IK = IC / 16;
  const int PS = 2128;  // shorts per ic-part (1064 dwords == 8 mod 32)
  const int NDY = K3 ? 3 : 1;
  const int NC = K3 ? 6 : 2;

  __shared__ __align__(16) short lds_hi[4 * 2128];
  __shared__ __align__(16) short lds_lo[4 * 2128];

  // staging address precompute (icC-invariant)
  int pixpart[5], wa[5];
  bool okv[5], wvalid[5];
  const size_t gbase = (size_t)b * HW * ICSTRIDE;
  #pragma unroll
  for (int i = 0; i < 5; ++i) {
    int idx = i * 256 + t;
    bool v5 = (i < 4) || (t < 32);
    int part = idx / 264;
    int pos = idx - part * 264;
    int srow = pos / 66, scol = pos - srow * 66;
    int gy = r0 + srow - 1, gx = scol - 1;
    bool ok = v5 && gy >= 0 && gy < 64 && gx >= 0 && gx < 64;
    if (!K3) ok = ok && (srow >= 1 && srow <= 2);
    okv[i] = ok; wvalid[i] = v5;
    pixpart[i] = (gy * 64 + gx) * ICSTRIDE + part * 8;
    wa[i] = part * PS + pos * 8;
  }
  const uint4v zv = {0u, 0u, 0u, 0u};
  uint4v rsh[5], rsl[5];

  auto issue_stage = [&](int icC2) {
    const int icoff = icbase + icC2 * 32;
    #pragma unroll
    for (int i = 0; i < 5; ++i) {
      if (okv[i]) {
        rsh[i] = *(const uint4v*)(in_hi + gbase + icoff + pixpart[i]);
        rsl[i] = *(const uint4v*)(in_lo + gbase + icoff + pixpart[i]);
      } else { rsh[i] = zv; rsl[i] = zv; }
    }
  };

  // A-fragment double buffer [buf][dy][of]
  short8v Ah[2][3][2], Al[2][3][2];
  auto loadA = [&](int icC2, int c) {
    const int buf = c & 1;             // compile-time after unroll
    const int dx = K3 ? (c >> 1) : 0;
    const int q  = K3 ? (c & 1) : c;
    #pragma unroll
    for (int dy = 0; dy < NDY; ++dy)
      #pragma unroll
      for (int of = 0; of < 2; ++of) {
        size_t wi = ((((size_t)(K3 ? (dy * 3 + dx) : 0) * OCT32) + (z * 4 + ocg * 2 + of)) * IK
                     + (icC2 * 2 + q)) * 64 + lane;
        Ah[buf][dy][of] = *(const short8v*)(wp_hi + wi * 8);
        Al[buf][dy][of] = *(const short8v*)(wp_lo + wi * 8);
      }
  };

  float16v acc[2][2];
  #pragma unroll
  for (int of = 0; of < 2; ++of)
    #pragma unroll
    for (int pt = 0; pt < 2; ++pt)
      #pragma unroll
      for (int k = 0; k < 16; ++k) acc[of][pt][k] = 0.f;

  issue_stage(0);
  loadA(0, 0);

  for (int icC = 0; icC < ICC; ++icC) {
    __syncthreads();
    #pragma unroll
    for (int i = 0; i < 5; ++i) {
      if (wvalid[i]) {
        *(uint4v*)(lds_hi + wa[i]) = rsh[i];
        *(uint4v*)(lds_lo + wa[i]) = rsl[i];
      }
    }
    __syncthreads();

    #pragma unroll
    for (int c = 0; c < NC; ++c) {
      const int buf = c & 1;
      const int dx = K3 ? (c >> 1) : 0;
      const int q  = K3 ? (c & 1) : c;
      // prefetch next cluster's A (cross-icC at the tail)
      if (c < NC - 1) loadA(icC, c + 1);
      else if (icC + 1 < ICC) loadA(icC + 1, 0);
      // T14: issue next-icC staging once per icC, after c=1's A-loads in FIFO
      if (c == 0 && icC + 1 < ICC) issue_stage(icC + 1);

      if (K3) {
        #pragma unroll
        for (int sr = 0; sr < 4; ++sr) {
          int pix = sr * 66 + colg * 32 + dx + l31;
          int addr = (q * 2 + hl) * PS + pix * 8;
          short8v Bh = *(const short8v*)(lds_hi + addr);
          short8v Bl = *(const short8v*)(lds_lo + addr);
          #pragma unroll
          for (int dy = 0; dy < 3; ++dy) {
            int pt = sr - dy;
            if (pt < 0 || pt > 1) continue;  // compile-time
            acc[0][pt] = __builtin_amdgcn_mfma_f32_32x32x16_bf16(Ah[buf][dy][0], Bh, acc[0][pt], 0, 0, 0);
            acc[1][pt] = __builtin_amdgcn_mfma_f32_32x32x16_bf16(Ah[buf][dy][1], Bh, acc[1][pt], 0, 0, 0);
            acc[0][pt] = __builtin_amdgcn_mfma_f32_32x32x16_bf16(Al[buf][dy][0], Bh, acc[0][pt], 0, 0, 0);
            acc[1][pt] = __builtin_amdgcn_mfma_f32_32x32x16_bf16(Al[buf][dy][1], Bh, acc[1][pt], 0, 0, 0);
            acc[0][pt] = __builtin_amdgcn_mfma_f32_32x32x16_bf16(Ah[buf][dy][0], Bl, acc[0][pt], 0, 0, 0);
            acc[1][pt] = __builtin_amdgcn_mfma_f32_32x32x16_bf16(Ah[buf][dy][1], Bl, acc[1][pt], 0, 0, 0);
          }
        }
      } else {
        #pragma unroll
        for (int pt = 0; pt < 2; ++pt) {
          int pix = (pt + 1) * 66 + 1 + colg * 32 + l31;
          int addr = (q * 2 + hl) * PS + pix * 8;
          short8v Bh = *(const short8v*)(lds_hi + addr);
          short8v Bl = *(const short8v*)(lds_lo + addr);
          acc[0][pt] = __builtin_amdgcn_mfma_f32_32x32x16_bf16(Ah[buf][0][0], Bh, acc[0][pt], 0, 0, 0);
          acc[1][pt] = __builtin_amdgcn_mfma_f32_32x32x16_bf16(Ah[buf][0][1], Bh, acc[1][pt], 0, 0, 0);
          acc[0][pt] = __builtin_amdgcn_mfma_f32_32x32x16_bf16(Al[buf][0][0], Bh, acc[0][pt], 0, 0, 0);
          acc[1][pt] = __builtin_amdgcn_mfma_f32_32x32x16_bf16(Al[buf][0][1], Bh, acc[1][pt], 0, 0, 0);
          acc[0][pt] = __builtin_amdgcn_mfma_f32_32x32x16_bf16(Ah[buf][0][0], Bl, acc[0][pt], 0, 0, 0);
          acc[1][pt] = __builtin_amdgcn_mfma_f32_32x32x16_bf16(Ah[buf][0][1], Bl, acc[1][pt], 0, 0, 0);
        }
      }
    }
  }

  if (GBMODE) {
    #pragma unroll
    for (int of = 0; of < 2; ++of) {
      int cb = z * 64 + ocg * 32 + of * 16 + 4 * hl;
      #pragma unroll
      for (int quad = 0; quad < 2; ++quad) {
        int c0 = cb + quad * 8;
        float muv[4], rsv[4], gbv[4], bbv[4], ssv[4];
        #pragma unroll
        for (int r4 = 0; r4 < 4; ++r4) {
          int c = c0 + r4;
          muv[r4] = mu[b * C + c]; rsv[r4] = rstd[b * C + c];
          gbv[r4] = gbias[c]; bbv[r4] = bbias[c]; ssv[r4] = sscale[b * C + c];
        }
        #pragma unroll
        for (int pt = 0; pt < 2; ++pt) {
          int px = (r0 + pt) * 64 + colg * 32 + l31;
          short4v hs, ls;
          #pragma unroll
          for (int r4 = 0; r4 < 4; ++r4) {
            int rg = quad * 8 + r4;
            float g  = acc[of][pt][rg] + gbv[r4];
            float bt = acc[of][pt][rg + 4] + bbv[r4];
            float nv = (src[((size_t)(b * C + c0 + r4)) * HW + px] - muv[r4]) * rsv[r4];
            float v = nv * (1.f + g) + bt;
            if (LRELU) v = (v >= 0.f) ? v : 0.2f * v;
            v *= ssv[r4];
            short h = f2bf(v);
            hs[r4] = h;
            ls[r4] = f2bf(v - bf2f(h));
          }
          size_t o = ((size_t)b * HW + px) * C + c0;
          *(short4v*)(out_hi + o) = hs;
          *(short4v*)(out_lo + o) = ls;
        }
      }
    }
  } else {
    #pragma unroll
    for (int of = 0; of < 2; ++of) {
      int ocb = z * 128 + ocg * 64 + of * 32 + 4 * hl;
      float ds[16];
      #pragma unroll
      for (int r = 0; r < 16; ++r)
        ds[r] = dscale[b * 256 + ocb + (r & 3) + 8 * (r >> 2)];
      #pragma unroll
      for (int pt = 0; pt < 2; ++pt) {
        int px = (r0 + pt) * 64 + colg * 32 + l31;
        #pragma unroll
        for (int r = 0; r < 16; ++r) {
          int oc = ocb + (r & 3) + 8 * (r >> 2);
          size_t oi = ((size_t)b * 256 + oc) * HW + px;
          float v = acc[of][pt][r] * ds[r];
          if (ACCUM) v += outF[oi];
          outF[oi] = v;
        }
      }
    }
  }
}

extern "C" void kernel_launch(void* const* d_in, const int* in_sizes, int n_in,
                              void* d_out, int out_size, void* d_ws, size_t ws_size,
                              hipStream_t stream) {
  const float* x     = (const float*)d_in[0];
  const float* seg   = (const float*)d_in[1];
  const float* style = (const float*)d_in[2];
  const float* n0_sw = (const float*)d_in[3];
  const float* n0_sb = (const float*)d_in[4];
  const float* n0_gw = (const float*)d_in[5];
  const float* n0_gb = (const float*)d_in[6];
  const float* n0_bw = (const float*)d_in[7];
  const float* n0_bb = (const float*)d_in[8];
  const float* n1_sw = (const float*)d_in[9];
  const float* n1_sb = (const float*)d_in[10];
  const float* n1_gw = (const float*)d_in[11];
  const float* n1_gb = (const float*)d_in[12];
  const float* n1_bw = (const float*)d_in[13];
  const float* n1_bb = (const float*)d_in[14];
  const float* ns_sw = (const float*)d_in[15];
  const float* ns_sb = (const float*)d_in[16];
  const float* ns_gw = (const float*)d_in[17];
  const float* ns_gb = (const float*)d_in[18];
  const float* ns_bw = (const float*)d_in[19];
  const float* ns_bb = (const float*)d_in[20];
  const float* w0  = (const float*)d_in[21];
  const float* m0w = (const float*)d_in[22];
  const float* m0b = (const float*)d_in[23];
  const float* w1  = (const float*)d_in[24];
  const float* m1w = (const float*)d_in[25];
  const float* m1b = (const float*)d_in[26];
  const float* wss = (const float*)d_in[27];
  const float* msw = (const float*)d_in[28];
  const float* msb = (const float*)d_in[29];
  float* out = (float*)d_out;

  char* p = (char*)d_ws;
  auto allocF = [&](size_t n) { float* r = (float*)p; p += n * 4; return r; };
  auto allocS = [&](size_t n) { short* r = (short*)p; p += n * 2; return r; };

  float* mu_x   = allocF(4096);
  float* rstd_x = allocF(4096);
  float* mu_h   = allocF(2048);
  float* rstd_h = allocF(2048);
  float* s0  = allocF(4096);
  float* s1  = allocF(2048);
  float* ss  = allocF(4096);
  float* d0  = allocF(2048);
  float* d1  = allocF(2048);
  float* dss = allocF(2048);
  float* wsq0 = allocF(256 * 512);
  float* wsq1 = allocF(256 * 256);
  float* wsqs = allocF(256 * 512);
  float* bufH = allocF((size_t)BN * 256 * HW);
  short* actv_hi = allocS((size_t)BN * HW * 384);   // sets: 0=n0, 1=n1, 2=ns
  short* actv_lo = allocS((size_t)BN * HW * 384);
  short* sp_hi = allocS((size_t)BN * HW * 512);
  short* sp_lo = allocS((size_t)BN * HW * 512);
  short* p0h = allocS((size_t)256 * 512 * 9);
  short* p0l = allocS((size_t)256 * 512 * 9);
  short* p1h = allocS((size_t)256 * 256 * 9);
  short* p1l = allocS((size_t)256 * 256 * 9);
  short* psh = allocS((size_t)256 * 512);
  short* psl = allocS((size_t)256 * 512);
  short* pgsh = allocS((size_t)1024 * 128 * 9);
  short* pgsl = allocS((size_t)1024 * 128 * 9);
  short* pg0h = allocS((size_t)1024 * 128 * 9);
  short* pg0l = allocS((size_t)1024 * 128 * 9);
  short* pg1h = allocS((size_t)512 * 128 * 9);
  short* pg1l = allocS((size_t)512 * 128 * 9);

  float cs0 = 1.0f / sqrtf(512.f * 9.f);
  float cs1 = 1.0f / sqrtf(256.f * 9.f);
  float css = 1.0f / sqrtf(512.f);

  // -------- small precompute --------
  stats_kernel<<<BN * 512, 256, 0, stream>>>(x, mu_x, rstd_x);
  modscale_kernel<<<(BN * 512) / 256, 256, 0, stream>>>(style, m0w, m0b, s0, 512);
  modscale_kernel<<<(BN * 256) / 256, 256, 0, stream>>>(style, m1w, m1b, s1, 256);
  modscale_kernel<<<(BN * 512) / 256, 256, 0, stream>>>(style, msw, msb, ss, 512);
  wsq_kernel<<<(256 * 512) / 256, 256, 0, stream>>>(w0, wsq0, 256 * 512, 9);
  wsq_kernel<<<(256 * 256) / 256, 256, 0, stream>>>(w1, wsq1, 256 * 256, 9);
  wsq_kernel<<<(256 * 512) / 256, 256, 0, stream>>>(wss, wsqs, 256 * 512, 1);
  demod_kernel<<<8, 256, 0, stream>>>(wsq0, s0, d0, 512, cs0);
  demod_kernel<<<8, 256, 0, stream>>>(wsq1, s1, d1, 256, cs1);
  demod_kernel<<<8, 256, 0, stream>>>(wsqs, ss, dss, 512, css);

  // -------- weight packing (32x32 fragment layout) --------
  pack_w32_kernel<<<576, 256, 0, stream>>>(w0, nullptr, p0h, p0l, 256, 512, 9, 0);
  pack_w32_kernel<<<288, 256, 0, stream>>>(w1, nullptr, p1h, p1l, 256, 256, 9, 0);
  pack_w32_kernel<<<64,  256, 0, stream>>>(wss, nullptr, psh, psl, 256, 512, 1, 0);
  pack_w32_kernel<<<576, 256, 0, stream>>>(ns_gw, ns_bw, pgsh, pgsl, 1024, 128, 9, 1);
  pack_w32_kernel<<<576, 256, 0, stream>>>(n0_gw, n0_bw, pg0h, pg0l, 1024, 128, 9, 1);
  pack_w32_kernel<<<288, 256, 0, stream>>>(n1_gw, n1_bw, pg1h, pg1l, 512, 128, 9, 1);

  // -------- all 3 seg convs in one dispatch --------
  seg_conv_all_kernel<<<dim3(BN, 4, 24), 256, 0, stream>>>(
      seg, n0_sw, n0_sb, n1_sw, n1_sb, ns_sw, ns_sb, actv_hi, actv_lo);

  // -------- shortcut: spade_ns (no lrelu, set 2) -> 1x1 modconv -> d_out --------
  conv32_kernel<128, 384, 1, 1, 0, 0><<<dim3(BN, 32, 8), 256, 0, stream>>>(
      actv_hi, actv_lo, pgsh, pgsl, nullptr, x, mu_x, rstd_x, ns_gb, ns_bb, ss,
      nullptr, sp_hi, sp_lo, 32, 512, 256);
  conv32_kernel<512, 512, 0, 0, 0, 0><<<dim3(BN, 32, 2), 256, 0, stream>>>(
      sp_hi, sp_lo, psh, psl, dss, nullptr, nullptr, nullptr, nullptr, nullptr,
      nullptr, out, nullptr, nullptr, 8, 256, 0);

  // -------- main: spade_n0 (lrelu, set 0) -> modconv0 -> bufH --------
  conv32_kernel<128, 384, 1, 1, 1, 0><<<dim3(BN, 32, 8), 256, 0, stream>>>(
      actv_hi, actv_lo, pg0h, pg0l, nullptr, x, mu_x, rstd_x, n0_gb, n0_bb, s0,
      nullptr, sp_hi, sp_lo, 32, 512, 0);
  conv32_kernel<512, 512, 1, 0, 0, 0><<<dim3(BN, 32, 2), 256, 0, stream>>>(
      sp_hi, sp_lo, p0h, p0l, d0, nullptr, nullptr, nullptr, nullptr, nullptr,
      nullptr, bufH, nullptr, nullptr, 8, 256, 0);

  // -------- spade_n1 over bufH (lrelu, set 1) -> modconv1 (+= into d_out) --------
  stats_kernel<<<BN * 256, 256, 0, stream>>>(bufH, mu_h, rstd_h);
  conv32_kernel<128, 384, 1, 1, 1, 0><<<dim3(BN, 32, 4), 256, 0, stream>>>(
      actv_hi, actv_lo, pg1h, pg1l, nullptr, bufH, mu_h, rstd_h, n1_gb, n1_bb, s1,
      nullptr, sp_hi, sp_lo, 16, 256, 128);
  conv32_kernel<256, 256, 1, 0, 0, 1><<<dim3(BN, 32, 2), 256, 0, stream>>>(
      sp_hi, sp_lo, p1h, p1l, d1, nullptr, nullptr, nullptr, nullptr, nullptr,
      nullptr, out, nullptr, nullptr, 8, 256, 0);
}

// Round 8
// 1170.078 us; speedup vs baseline: 1.4066x; 1.4066x over previous
//
#include <hip/hip_runtime.h>
#include <math.h>

#define BN 8
#define HW 4096
#define NH 128
#define SNC 35
#define SD 512

typedef __attribute__((ext_vector_type(8))) short short8v;
typedef __attribute__((ext_vector_type(4))) float float4v;
typedef __attribute__((ext_vector_type(4))) unsigned int uint4v;

__device__ __forceinline__ short f2bf(float f) {
  unsigned u = __float_as_uint(f);
  unsigned r = (u + 0x7fffu + ((u >> 16) & 1u)) >> 16;
  return (short)r;
}
__device__ __forceinline__ float bf2f(short h) {
  return __uint_as_float(((unsigned)(unsigned short)h) << 16);
}

// ---------------- per-(b,c) instance-norm stats ----------------
__global__ __launch_bounds__(256) void stats_kernel(const float* __restrict__ x,
                                                    float* __restrict__ mu,
                                                    float* __restrict__ rstd) {
  int row = blockIdx.x;
  const float* p = x + (size_t)row * HW;
  float s = 0.f, s2 = 0.f;
  for (int i = threadIdx.x; i < HW; i += 256) {
    float v = p[i];
    s += v; s2 += v * v;
  }
  #pragma unroll
  for (int off = 32; off > 0; off >>= 1) {
    s  += __shfl_down(s, off);
    s2 += __shfl_down(s2, off);
  }
  __shared__ float as[4], as2[4];
  int wid = threadIdx.x >> 6;
  if ((threadIdx.x & 63) == 0) { as[wid] = s; as2[wid] = s2; }
  __syncthreads();
  if (threadIdx.x == 0) {
    float t  = as[0] + as[1] + as[2] + as[3];
    float t2 = as2[0] + as2[1] + as2[2] + as2[3];
    float m = t * (1.f / HW);
    float var = t2 * (1.f / HW) - m * m;
    mu[row] = m;
    rstd[row] = rsqrtf(var + 1e-5f);
  }
}

// ---------------- style modulation s[b,i] ----------------
__global__ __launch_bounds__(256) void modscale_kernel(const float* __restrict__ style,
                                                       const float* __restrict__ mw,
                                                       const float* __restrict__ mb,
                                                       float* __restrict__ s_out, int I) {
  int idx = blockIdx.x * 256 + threadIdx.x;
  if (idx >= BN * I) return;
  int b = idx / I, i = idx - b * I;
  const float* st = style + (size_t)b * SD;
  const float* w  = mw + (size_t)i * SD;
  float acc = 0.f;
  for (int d = 0; d < SD; ++d) acc += st[d] * w[d];
  s_out[idx] = acc * 0.044194173824159216f + mb[i];
}

// ---------------- sum of w^2 over taps ----------------
__global__ __launch_bounds__(256) void wsq_kernel(const float* __restrict__ w,
                                                  float* __restrict__ wsq, int n, int KK) {
  int idx = blockIdx.x * 256 + threadIdx.x;
  if (idx >= n) return;
  const float* p = w + (size_t)idx * KK;
  float a = 0.f;
  for (int t = 0; t < KK; ++t) a += p[t] * p[t];
  wsq[idx] = a;
}

// ---------------- dscale[b,o] = demod * conv_scale ----------------
__global__ __launch_bounds__(256) void demod_kernel(const float* __restrict__ wsq,
                                                    const float* __restrict__ s,
                                                    float* __restrict__ dscale,
                                                    int I, float cs) {
  int idx = blockIdx.x * 256 + threadIdx.x;
  if (idx >= BN * 256) return;
  int b = idx >> 8, o = idx & 255;
  const float* wr = wsq + (size_t)o * I;
  const float* sr = s + (size_t)b * I;
  float a = 0.f;
  for (int i = 0; i < I; ++i) { float sv = sr[i]; a += wr[i] * sv * sv; }
  float demod = rsqrtf(cs * cs * a + 1e-8f);
  dscale[idx] = demod * cs;
}

// ---------------- weight pack+split: w[oc][ic][tap] -> fragment-major bf16 hi/lo ----------------
// packed[((tap*OCT16 + ocT)*ICC + icC)*64 + lane][8]
// lane: oc = ocT*16 + (lane&15), ic = icC*32 + (lane>>4)*8 + j
// interleave: packed oc index po -> (c = po>>1, tensor = po&1 ? wb : wg)
__global__ __launch_bounds__(256) void pack_w_kernel(const float* __restrict__ wg,
                                                     const float* __restrict__ wb,
                                                     short* __restrict__ ph,
                                                     short* __restrict__ pl,
                                                     int OCtot, int IC, int KK,
                                                     int interleave) {
  int tid = blockIdx.x * 256 + threadIdx.x;
  int ICC = IC / 32, OCT16 = OCtot / 16;
  int total = KK * OCT16 * ICC * 64;
  if (tid >= total) return;
  int lane = tid & 63;
  int r = tid >> 6;
  int icC = r % ICC; r /= ICC;
  int ocT = r % OCT16; int tap = r / OCT16;
  int po = ocT * 16 + (lane & 15);
  int ic0 = icC * 32 + (lane >> 4) * 8;
  const float* srcw;
  int oc;
  if (interleave) { oc = po >> 1; srcw = (po & 1) ? wb : wg; }
  else { oc = po; srcw = wg; }
  short8v hv, lv;
  #pragma unroll
  for (int j = 0; j < 8; ++j) {
    float v = srcw[((size_t)oc * IC + ic0 + j) * KK + tap];
    short h = f2bf(v);
    hv[j] = h;
    lv[j] = f2bf(v - bf2f(h));
  }
  size_t o = (size_t)tid * 8;
  *(short8v*)(ph + o) = hv;
  *(short8v*)(pl + o) = lv;
}

// ---------------- all 3 seg convs (35->3x128) 3x3 + bias + relu, pixel-major bf16 (hi only) [B][HW][384] ----------------
__global__ __launch_bounds__(256) void seg_conv_all_kernel(
    const float* __restrict__ seg,
    const float* __restrict__ sw0, const float* __restrict__ sb0,
    const float* __restrict__ sw1, const float* __restrict__ sb1,
    const float* __restrict__ sw2, const float* __restrict__ sb2,
    short* __restrict__ actv_hi) {
  const int b = blockIdx.x;
  const int ty0 = (blockIdx.y >> 1) * 32, tx0 = (blockIdx.y & 1) * 32;
  const int s = blockIdx.z >> 3;
  const int oc0 = (blockIdx.z & 7) * 16;
  const float* sw = (s == 0) ? sw0 : ((s == 1) ? sw1 : sw2);
  const float* sb = (s == 0) ? sb0 : ((s == 1) ? sb1 : sb2);
  const int t = threadIdx.x;
  const int c = t & 31;
  const int r0 = (t >> 5) * 4;
  __shared__ float lds_in[12 * 34 * 34];
  __shared__ float lds_w[12 * 9 * 16];
  float acc[4][16];
  #pragma unroll
  for (int q = 0; q < 4; ++q)
    #pragma unroll
    for (int o = 0; o < 16; ++o) acc[q][o] = 0.f;

  for (int ic0 = 0; ic0 < SNC; ic0 += 12) {
    int icc = (SNC - ic0 < 12) ? (SNC - ic0) : 12;
    __syncthreads();
    for (int idx = t; idx < icc * 34 * 34; idx += 256) {
      int ic = idx / (34 * 34);
      int rem = idx - ic * (34 * 34);
      int y = rem / 34, xx = rem - y * 34;
      int gy = ty0 + y - 1, gx = tx0 + xx - 1;
      float v = 0.f;
      if (gy >= 0 && gy < 64 && gx >= 0 && gx < 64)
        v = seg[(((size_t)b * SNC + ic0 + ic) * 64 + gy) * 64 + gx];
      lds_in[idx] = v;
    }
    for (int idx = t; idx < icc * 9 * 16; idx += 256) {
      int oc = idx & 15;
      int rest = idx >> 4;
      int ic = rest / 9, tau = rest - ic * 9;
      lds_w[idx] = sw[((size_t)(oc0 + oc) * SNC + ic0 + ic) * 9 + tau];
    }
    __syncthreads();
    for (int ic = 0; ic < icc; ++ic) {
      #pragma unroll
      for (int kh = 0; kh < 3; ++kh) {
        int base = (ic * 34 + r0 + kh) * 34 + c;
        #pragma unroll
        for (int kw = 0; kw < 3; ++kw) {
          float a0 = lds_in[base + kw];
          float a1 = lds_in[base + kw + 34];
          float a2 = lds_in[base + kw + 68];
          float a3 = lds_in[base + kw + 102];
          const float* wp = &lds_w[(ic * 9 + kh * 3 + kw) * 16];
          float wv[16];
          *(float4*)&wv[0]  = *(const float4*)&wp[0];
          *(float4*)&wv[4]  = *(const float4*)&wp[4];
          *(float4*)&wv[8]  = *(const float4*)&wp[8];
          *(float4*)&wv[12] = *(const float4*)&wp[12];
          #pragma unroll
          for (int o = 0; o < 16; ++o) {
            acc[0][o] += a0 * wv[o];
            acc[1][o] += a1 * wv[o];
            acc[2][o] += a2 * wv[o];
            acc[3][o] += a3 * wv[o];
          }
        }
      }
    }
  }
  float bias[16];
  #pragma unroll
  for (int o = 0; o < 16; ++o) bias[o] = sb[oc0 + o];
  #pragma unroll
  for (int q = 0; q < 4; ++q) {
    int px = (ty0 + r0 + q) * 64 + tx0 + c;
    short8v h0, h1;
    #pragma unroll
    for (int o = 0; o < 8; ++o) {
      float v = fmaxf(acc[q][o] + bias[o], 0.f);
      h0[o] = f2bf(v);
      float v2 = fmaxf(acc[q][o + 8] + bias[o + 8], 0.f);
      h1[o] = f2bf(v2);
    }
    size_t o0 = ((size_t)b * HW + px) * 384 + s * 128 + oc0;
    *(short8v*)(actv_hi + o0) = h0;
    *(short8v*)(actv_hi + o0 + 8) = h1;
  }
}

// ---------------- MFMA split-precision implicit-GEMM conv (round-4 structure) ----------------
// LDS part stride 2128 shorts = 1064 dwords (== 8 mod 32). K3 path: dx outer,
// staged-row sr inner; one B read serves all dy (row-shared).
// INLO=0: input has no lo part (2 MFMAs: Ah*Bh + Al*Bh); INLO=1: 3 MFMAs.
template<int IC, int ICSTRIDE, int K3, int GBMODE, int LRELU, int ACCUM, int INLO>
__global__ __launch_bounds__(256) void conv_mfma_kernel(
    const short* __restrict__ in_hi, const short* __restrict__ in_lo,
    const short* __restrict__ wp_hi, const short* __restrict__ wp_lo,
    const float* __restrict__ dscale,
    const float* __restrict__ src, const float* __restrict__ mu,
    const float* __restrict__ rstd, const float* __restrict__ gbias,
    const float* __restrict__ bbias, const float* __restrict__ sscale,
    float* __restrict__ outF, short* __restrict__ out_hi,
    short* __restrict__ out_lo, int OCT16, int C, int icbase) {
  const int b = blockIdx.x;
  const int r0 = blockIdx.y * 2;
  const int z = blockIdx.z;
  const int t = threadIdx.x;
  const int wv = t >> 6;
  const int lane = t & 63;
  const int l15 = lane & 15, lg = lane >> 4;
  const int ICC = IC / 32;
  const int PS = 2128;  // shorts per part; 1064 dwords == 8 (mod 32)

  __shared__ __align__(16) short lds_hi[4 * 2128];
  __shared__ __align__(16) short lds_lo[INLO ? 4 * 2128 : 8];

  float4v acc[2][8];
  #pragma unroll
  for (int a = 0; a < 2; ++a)
    #pragma unroll
    for (int pt = 0; pt < 8; ++pt) acc[a][pt] = (float4v){0.f, 0.f, 0.f, 0.f};

  for (int icC = 0; icC < ICC; ++icC) {
    __syncthreads();
    const int ic0 = icC * 32;
    for (int idx = t; idx < 264 * 4; idx += 256) {
      int pos = idx >> 2, part = idx & 3;
      int srow = pos / 66;
      int scol = pos - srow * 66;
      int gy = r0 + srow - 1, gx = scol - 1;
      uint4v vh = {0u, 0u, 0u, 0u}, vl = {0u, 0u, 0u, 0u};
      bool ok = (gy >= 0 && gy < 64 && gx >= 0 && gx < 64);
      if (!K3) ok = ok && (srow >= 1 && srow <= 2);
      if (ok) {
        size_t g = ((size_t)b * HW + gy * 64 + gx) * ICSTRIDE + icbase + ic0 + part * 8;
        vh = *(const uint4v*)(in_hi + g);
        if (INLO) vl = *(const uint4v*)(in_lo + g);
      }
      int lo = part * PS + pos * 8;
      *(uint4v*)(lds_hi + lo) = vh;
      if (INLO) *(uint4v*)(lds_lo + lo) = vl;
    }
    __syncthreads();

    if (K3) {
      #pragma unroll
      for (int dx = 0; dx < 3; ++dx) {
        short8v Ah[3][2], Al[3][2];
        #pragma unroll
        for (int dy = 0; dy < 3; ++dy) {
          #pragma unroll
          for (int a = 0; a < 2; ++a) {
            size_t wi = ((((size_t)(dy * 3 + dx) * OCT16) + (z * 8 + wv * 2 + a)) * ICC + icC) * 64 + lane;
            Ah[dy][a] = *(const short8v*)(wp_hi + wi * 8);
            Al[dy][a] = *(const short8v*)(wp_lo + wi * 8);
          }
        }
        #pragma unroll
        for (int c0i = 0; c0i < 4; ++c0i) {
          #pragma unroll
          for (int sr = 0; sr < 4; ++sr) {
            int pix = sr * 66 + c0i * 16 + dx + l15;
            int addr = lg * PS + pix * 8;
            short8v Bh = *(const short8v*)(lds_hi + addr);
            #pragma unroll
            for (int dy = 0; dy < 3; ++dy) {
              int pt = sr - dy;
              if (pt < 0 || pt > 1) continue;  // compile-time
              int p = dy; (void)p;
              int ptt = pt * 4 + c0i;
              acc[0][ptt] = __builtin_amdgcn_mfma_f32_16x16x32_bf16(Ah[dy][0], Bh, acc[0][ptt], 0, 0, 0);
              acc[1][ptt] = __builtin_amdgcn_mfma_f32_16x16x32_bf16(Ah[dy][1], Bh, acc[1][ptt], 0, 0, 0);
              acc[0][ptt] = __builtin_amdgcn_mfma_f32_16x16x32_bf16(Al[dy][0], Bh, acc[0][ptt], 0, 0, 0);
              acc[1][ptt] = __builtin_amdgcn_mfma_f32_16x16x32_bf16(Al[dy][1], Bh, acc[1][ptt], 0, 0, 0);
            }
            if (INLO) {
              short8v Bl = *(const short8v*)(lds_lo + addr);
              #pragma unroll
              for (int dy = 0; dy < 3; ++dy) {
                int pt = sr - dy;
                if (pt < 0 || pt > 1) continue;
                int ptt = pt * 4 + c0i;
                acc[0][ptt] = __builtin_amdgcn_mfma_f32_16x16x32_bf16(Ah[dy][0], Bl, acc[0][ptt], 0, 0, 0);
                acc[1][ptt] = __builtin_amdgcn_mfma_f32_16x16x32_bf16(Ah[dy][1], Bl, acc[1][ptt], 0, 0, 0);
              }
            }
          }
        }
      }
    } else {
      short8v Ah[2], Al[2];
      #pragma unroll
      for (int a = 0; a < 2; ++a) {
        size_t wi = (((size_t)(z * 8 + wv * 2 + a)) * ICC + icC) * 64 + lane;
        Ah[a] = *(const short8v*)(wp_hi + wi * 8);
        Al[a] = *(const short8v*)(wp_lo + wi * 8);
      }
      #pragma unroll
      for (int pt = 0; pt < 8; ++pt) {
        int pix = ((pt >> 2) + 1) * 66 + (pt & 3) * 16 + 1 + l15;
        int addr = lg * PS + pix * 8;
        short8v Bh = *(const short8v*)(lds_hi + addr);
        acc[0][pt] = __builtin_amdgcn_mfma_f32_16x16x32_bf16(Ah[0], Bh, acc[0][pt], 0, 0, 0);
        acc[1][pt] = __builtin_amdgcn_mfma_f32_16x16x32_bf16(Ah[1], Bh, acc[1][pt], 0, 0, 0);
        acc[0][pt] = __builtin_amdgcn_mfma_f32_16x16x32_bf16(Al[0], Bh, acc[0][pt], 0, 0, 0);
        acc[1][pt] = __builtin_amdgcn_mfma_f32_16x16x32_bf16(Al[1], Bh, acc[1][pt], 0, 0, 0);
        if (INLO) {
          short8v Bl = *(const short8v*)(lds_lo + addr);
          acc[0][pt] = __builtin_amdgcn_mfma_f32_16x16x32_bf16(Ah[0], Bl, acc[0][pt], 0, 0, 0);
          acc[1][pt] = __builtin_amdgcn_mfma_f32_16x16x32_bf16(Ah[1], Bl, acc[1][pt], 0, 0, 0);
        }
      }
    }
  }

  if (GBMODE) {
    #pragma unroll
    for (int a = 0; a < 2; ++a) {
      int base = z * 128 + wv * 32 + a * 16 + lg * 4;
      int cA = base >> 1;
      int cB = cA + 1;
      float muA = mu[b * C + cA], rsA = rstd[b * C + cA];
      float gbA = gbias[cA], bbA = bbias[cA], sA = sscale[b * C + cA];
      float muB = mu[b * C + cB], rsB = rstd[b * C + cB];
      float gbB = gbias[cB], bbB = bbias[cB], sB = sscale[b * C + cB];
      const float* srcA = src + ((size_t)b * C + cA) * HW;
      const float* srcB = src + ((size_t)b * C + cB) * HW;
      #pragma unroll
      for (int pt = 0; pt < 8; ++pt) {
        int px = (r0 + (pt >> 2)) * 64 + (pt & 3) * 16 + l15;
        float nvA = (srcA[px] - muA) * rsA;
        float vA = nvA * (1.f + acc[a][pt][0] + gbA) + acc[a][pt][1] + bbA;
        if (LRELU) vA = (vA >= 0.f) ? vA : 0.2f * vA;
        vA *= sA;
        float nvB = (srcB[px] - muB) * rsB;
        float vB = nvB * (1.f + acc[a][pt][2] + gbB) + acc[a][pt][3] + bbB;
        if (LRELU) vB = (vB >= 0.f) ? vB : 0.2f * vB;
        vB *= sB;
        short hA = f2bf(vA), hB = f2bf(vB);
        short lA = f2bf(vA - bf2f(hA)), lB = f2bf(vB - bf2f(hB));
        size_t o = ((size_t)b * HW + px) * C + cA;
        *(unsigned*)(out_hi + o) =
            (unsigned)(unsigned short)hA | ((unsigned)(unsigned short)hB << 16);
        *(unsigned*)(out_lo + o) =
            (unsigned)(unsigned short)lA | ((unsigned)(unsigned short)lB << 16);
      }
    }
  } else {
    #pragma unroll
    for (int a = 0; a < 2; ++a) {
      int ocbase = z * 128 + wv * 32 + a * 16 + lg * 4;
      float ds[4];
      #pragma unroll
      for (int r = 0; r < 4; ++r) ds[r] = dscale[b * 256 + ocbase + r];
      #pragma unroll
      for (int pt = 0; pt < 8; ++pt) {
        int px = (r0 + (pt >> 2)) * 64 + (pt & 3) * 16 + l15;
        #pragma unroll
        for (int r = 0; r < 4; ++r) {
          size_t oi = ((size_t)b * 256 + ocbase + r) * HW + px;
          float v = acc[a][pt][r] * ds[r];
          if (ACCUM) v += outF[oi];
          outF[oi] = v;
        }
      }
    }
  }
}

extern "C" void kernel_launch(void* const* d_in, const int* in_sizes, int n_in,
                              void* d_out, int out_size, void* d_ws, size_t ws_size,
                              hipStream_t stream) {
  const float* x     = (const float*)d_in[0];
  const float* seg   = (const float*)d_in[1];
  const float* style = (const float*)d_in[2];
  const float* n0_sw = (const float*)d_in[3];
  const float* n0_sb = (const float*)d_in[4];
  const float* n0_gw = (const float*)d_in[5];
  const float* n0_gb = (const float*)d_in[6];
  const float* n0_bw = (const float*)d_in[7];
  const float* n0_bb = (const float*)d_in[8];
  const float* n1_sw = (const float*)d_in[9];
  const float* n1_sb = (const float*)d_in[10];
  const float* n1_gw = (const float*)d_in[11];
  const float* n1_gb = (const float*)d_in[12];
  const float* n1_bw = (const float*)d_in[13];
  const float* n1_bb = (const float*)d_in[14];
  const float* ns_sw = (const float*)d_in[15];
  const float* ns_sb = (const float*)d_in[16];
  const float* ns_gw = (const float*)d_in[17];
  const float* ns_gb = (const float*)d_in[18];
  const float* ns_bw = (const float*)d_in[19];
  const float* ns_bb = (const float*)d_in[20];
  const float* w0  = (const float*)d_in[21];
  const float* m0w = (const float*)d_in[22];
  const float* m0b = (const float*)d_in[23];
  const float* w1  = (const float*)d_in[24];
  const float* m1w = (const float*)d_in[25];
  const float* m1b = (const float*)d_in[26];
  const float* wss = (const float*)d_in[27];
  const float* msw = (const float*)d_in[28];
  const float* msb = (const float*)d_in[29];
  float* out = (float*)d_out;

  char* p = (char*)d_ws;
  auto allocF = [&](size_t n) { float* r = (float*)p; p += n * 4; return r; };
  auto allocS = [&](size_t n) { short* r = (short*)p; p += n * 2; return r; };

  float* mu_x   = allocF(4096);
  float* rstd_x = allocF(4096);
  float* mu_h   = allocF(2048);
  float* rstd_h = allocF(2048);
  float* s0  = allocF(4096);
  float* s1  = allocF(2048);
  float* ss  = allocF(4096);
  float* d0  = allocF(2048);
  float* d1  = allocF(2048);
  float* dss = allocF(2048);
  float* wsq0 = allocF(256 * 512);
  float* wsq1 = allocF(256 * 256);
  float* wsqs = allocF(256 * 512);
  float* bufH = allocF((size_t)BN * 256 * HW);
  short* actv_hi = allocS((size_t)BN * HW * 384);   // sets: 0=n0, 1=n1, 2=ns (bf16 hi only)
  short* sp_hi = allocS((size_t)BN * HW * 512);
  short* sp_lo = allocS((size_t)BN * HW * 512);
  short* p0h = allocS((size_t)256 * 512 * 9);
  short* p0l = allocS((size_t)256 * 512 * 9);
  short* p1h = allocS((size_t)256 * 256 * 9);
  short* p1l = allocS((size_t)256 * 256 * 9);
  short* psh = allocS((size_t)256 * 512);
  short* psl = allocS((size_t)256 * 512);
  short* pgsh = allocS((size_t)1024 * 128 * 9);
  short* pgsl = allocS((size_t)1024 * 128 * 9);
  short* pg0h = allocS((size_t)1024 * 128 * 9);
  short* pg0l = allocS((size_t)1024 * 128 * 9);
  short* pg1h = allocS((size_t)512 * 128 * 9);
  short* pg1l = allocS((size_t)512 * 128 * 9);

  float cs0 = 1.0f / sqrtf(512.f * 9.f);
  float cs1 = 1.0f / sqrtf(256.f * 9.f);
  float css = 1.0f / sqrtf(512.f);

  // -------- small precompute --------
  stats_kernel<<<BN * 512, 256, 0, stream>>>(x, mu_x, rstd_x);
  modscale_kernel<<<(BN * 512) / 256, 256, 0, stream>>>(style, m0w, m0b, s0, 512);
  modscale_kernel<<<(BN * 256) / 256, 256, 0, stream>>>(style, m1w, m1b, s1, 256);
  modscale_kernel<<<(BN * 512) / 256, 256, 0, stream>>>(style, msw, msb, ss, 512);
  wsq_kernel<<<(256 * 512) / 256, 256, 0, stream>>>(w0, wsq0, 256 * 512, 9);
  wsq_kernel<<<(256 * 256) / 256, 256, 0, stream>>>(w1, wsq1, 256 * 256, 9);
  wsq_kernel<<<(256 * 512) / 256, 256, 0, stream>>>(wss, wsqs, 256 * 512, 1);
  demod_kernel<<<8, 256, 0, stream>>>(wsq0, s0, d0, 512, cs0);
  demod_kernel<<<8, 256, 0, stream>>>(wsq1, s1, d1, 256, cs1);
  demod_kernel<<<8, 256, 0, stream>>>(wsqs, ss, dss, 512, css);

  // -------- weight packing (16x16 fragment layout) --------
  pack_w_kernel<<<(9 * 16 * 16 * 64 + 255) / 256, 256, 0, stream>>>(w0, nullptr, p0h, p0l, 256, 512, 9, 0);
  pack_w_kernel<<<(9 * 16 * 8 * 64 + 255) / 256, 256, 0, stream>>>(w1, nullptr, p1h, p1l, 256, 256, 9, 0);
  pack_w_kernel<<<(1 * 16 * 16 * 64 + 255) / 256, 256, 0, stream>>>(wss, nullptr, psh, psl, 256, 512, 1, 0);
  pack_w_kernel<<<(9 * 64 * 4 * 64 + 255) / 256, 256, 0, stream>>>(ns_gw, ns_bw, pgsh, pgsl, 1024, 128, 9, 1);
  pack_w_kernel<<<(9 * 64 * 4 * 64 + 255) / 256, 256, 0, stream>>>(n0_gw, n0_bw, pg0h, pg0l, 1024, 128, 9, 1);
  pack_w_kernel<<<(9 * 32 * 4 * 64 + 255) / 256, 256, 0, stream>>>(n1_gw, n1_bw, pg1h, pg1l, 512, 128, 9, 1);

  // -------- all 3 seg convs in one dispatch (hi-only activations) --------
  seg_conv_all_kernel<<<dim3(BN, 4, 24), 256, 0, stream>>>(
      seg, n0_sw, n0_sb, n1_sw, n1_sb, ns_sw, ns_sb, actv_hi);

  // -------- shortcut: spade_ns (no lrelu, set 2) -> 1x1 modconv -> d_out --------
  conv_mfma_kernel<128, 384, 1, 1, 0, 0, 0><<<dim3(BN, 32, 8), 256, 0, stream>>>(
      actv_hi, nullptr, pgsh, pgsl, nullptr, x, mu_x, rstd_x, ns_gb, ns_bb, ss,
      nullptr, sp_hi, sp_lo, 64, 512, 256);
  conv_mfma_kernel<512, 512, 0, 0, 0, 0, 1><<<dim3(BN, 32, 2), 256, 0, stream>>>(
      sp_hi, sp_lo, psh, psl, dss, nullptr, nullptr, nullptr, nullptr, nullptr,
      nullptr, out, nullptr, nullptr, 16, 0, 0);

  // -------- main: spade_n0 (lrelu, set 0) -> modconv0 -> bufH --------
  conv_mfma_kernel<128, 384, 1, 1, 1, 0, 0><<<dim3(BN, 32, 8), 256, 0, stream>>>(
      actv_hi, nullptr, pg0h, pg0l, nullptr, x, mu_x, rstd_x, n0_gb, n0_bb, s0,
      nullptr, sp_hi, sp_lo, 64, 512, 0);
  conv_mfma_kernel<512, 512, 1, 0, 0, 0, 1><<<dim3(BN, 32, 2), 256, 0, stream>>>(
      sp_hi, sp_lo, p0h, p0l, d0, nullptr, nullptr, nullptr, nullptr, nullptr,
      nullptr, bufH, nullptr, nullptr, 16, 0, 0);

  // -------- spade_n1 over bufH (lrelu, set 1) -> modconv1 (+= into d_out) --------
  stats_kernel<<<BN * 256, 256, 0, stream>>>(bufH, mu_h, rstd_h);
  conv_mfma_kernel<128, 384, 1, 1, 1, 0, 0><<<dim3(BN, 32, 4), 256, 0, stream>>>(
      actv_hi, nullptr, pg1h, pg1l, nullptr, bufH, mu_h, rstd_h, n1_gb, n1_bb, s1,
      nullptr, sp_hi, sp_lo, 32, 256, 128);
  conv_mfma_kernel<256, 256, 1, 0, 0, 1, 1><<<dim3(BN, 32, 2), 256, 0, stream>>>(
      sp_hi, sp_lo, p1h, p1l, d1, nullptr, nullptr, nullptr, nullptr, nullptr,
      nullptr, out, nullptr, nullptr, 16, 0, 0);
}